// Round 7
// baseline (208.564 us; speedup 1.0000x reference)
//
#include <hip/hip_runtime.h>

typedef __attribute__((ext_vector_type(8))) short bf16x8;
typedef __attribute__((ext_vector_type(4))) float f32x4;
typedef __attribute__((ext_vector_type(16))) float f32x16;
typedef unsigned short u16;
typedef unsigned int u32;

#define MFMA16(a,b,c) __builtin_amdgcn_mfma_f32_16x16x32_bf16((a),(b),(c),0,0,0)
#define MFMA32(a,b,c) __builtin_amdgcn_mfma_f32_32x32x16_bf16((a),(b),(c),0,0,0)

#if __has_builtin(__builtin_amdgcn_exp2f)
#define EXP2(x) __builtin_amdgcn_exp2f(x)
#else
#define EXP2(x) __expf((x) * 0.6931471805599453f)
#endif

// f32 -> bf16 round-to-nearest-even
__device__ __forceinline__ u16 f2bf(float f) {
  u32 u = __builtin_bit_cast(u32, f);
  u += 0x7FFFu + ((u >> 16) & 1u);
  return (u16)(u >> 16);
}

// packed pair f32x2 -> bf16x2 (RNE) in one instruction
__device__ __forceinline__ u32 cvtpk(float lo, float hi) {
  u32 r;
  asm("v_cvt_pk_bf16_f32 %0, %1, %2" : "=v"(r) : "v"(lo), "v"(hi));
  return r;
}

// async 16B global -> LDS (dest must be wave-uniform base + lane*16)
__device__ __forceinline__ void gload16(const u16* g, u16* l) {
  __builtin_amdgcn_global_load_lds(
      (const __attribute__((address_space(1))) u32*)(const void*)g,
      (__attribute__((address_space(3))) u32*)(void*)l, 16, 0, 0);
}

// ---------------- x f32 -> bf16 ----------------
__global__ __launch_bounds__(256) void convert_x(const float* __restrict__ in,
                                                 u16* __restrict__ out, int n4) {
  int i = blockIdx.x * blockDim.x + threadIdx.x;
  int stride = gridDim.x * blockDim.x;
  for (; i < n4; i += stride) {
    float4 v = ((const float4*)in)[i];
    u32 lo = (u32)f2bf(v.x) | ((u32)f2bf(v.y) << 16);
    u32 hi = (u32)f2bf(v.z) | ((u32)f2bf(v.w) << 16);
    uint2 pv; pv.x = lo; pv.y = hi;
    ((uint2*)out)[i] = pv;
  }
}

// ---------------- W [R][C] f32 -> Wt [C][R] bf16 (R = 1024) ----------------
__global__ __launch_bounds__(256) void transpose_w(const float* __restrict__ in,
                                                   u16* __restrict__ out,
                                                   int R, int C) {
  __shared__ float t[32][33];
  int c0 = blockIdx.x * 32, r0 = blockIdx.y * 32;
  int tc = threadIdx.x & 31, tr = threadIdx.x >> 5;  // tr in 0..7
#pragma unroll
  for (int j = 0; j < 4; ++j) {
    int r = tr + j * 8;
    t[r][tc] = in[(size_t)(r0 + r) * C + c0 + tc];
  }
  __syncthreads();
#pragma unroll
  for (int j = 0; j < 4; ++j) {
    int cc = tr + j * 8;
    out[(size_t)(c0 + cc) * R + r0 + tc] = f2bf(t[tc][cc]);
  }
}

// ---------------- GEMM: C[M,n] = A[M,1024] * Bt[n,1024]^T + bias ----------------
// MODE 0: qkv with scatter epilogue -> Q,K [bh][2048][64], V transposed [bh][64][2048]
// MODE 1: f32 output [M][1024]
template <int MODE>
__global__ __launch_bounds__(256) void gemm_k(
    const u16* __restrict__ A, const u16* __restrict__ Bt,
    const float* __restrict__ bias,
    u16* __restrict__ Qo, u16* __restrict__ Ko, u16* __restrict__ Vt,
    float* __restrict__ Of) {
  __shared__ alignas(16) u16 As[128 * 32];
  __shared__ alignas(16) u16 Bs[128 * 32];
  const int tid = threadIdx.x;
  const int wid = tid >> 6, lane = tid & 63;
  const int g = lane >> 4, lr = lane & 15;
  const int m0 = blockIdx.y * 128, n0 = blockIdx.x * 128;
  const int wr = (wid >> 1) * 64, wc = (wid & 1) * 64;

  f32x4 acc[4][4];
#pragma unroll
  for (int i = 0; i < 4; ++i)
#pragma unroll
    for (int j = 0; j < 4; ++j) acc[i][j] = (f32x4){0.f, 0.f, 0.f, 0.f};

  const u16* Ab = A + (size_t)m0 * 1024;
  const u16* Bb = Bt + (size_t)n0 * 1024;

  for (int kt = 0; kt < 1024; kt += 32) {
#pragma unroll
    for (int i = 0; i < 2; ++i) {
      int s = tid + i * 256;           // 16B chunk id, 512 per tile
      int row = s >> 2, c = s & 3;     // 4 chunks per 32-elem row
      gload16(Ab + row * 1024 + kt + c * 8, As + s * 8);
      gload16(Bb + row * 1024 + kt + c * 8, Bs + s * 8);
    }
    __syncthreads();
    bf16x8 af[4], bfr[4];
#pragma unroll
    for (int i = 0; i < 4; ++i)
      af[i] = *(const bf16x8*)(As + (wr + i * 16 + lr) * 32 + g * 8);
#pragma unroll
    for (int j = 0; j < 4; ++j)
      bfr[j] = *(const bf16x8*)(Bs + (wc + j * 16 + lr) * 32 + g * 8);
    __builtin_amdgcn_s_setprio(1);
#pragma unroll
    for (int i = 0; i < 4; ++i)
#pragma unroll
      for (int j = 0; j < 4; ++j)
        acc[i][j] = MFMA16(af[i], bfr[j], acc[i][j]);
    __builtin_amdgcn_s_setprio(0);
    __syncthreads();
  }

  if constexpr (MODE == 1) {
#pragma unroll
    for (int i = 0; i < 4; ++i) {
      int row = m0 + wr + i * 16 + g * 4;
#pragma unroll
      for (int j = 0; j < 4; ++j) {
        int col = n0 + wc + j * 16 + lr;
        float bv = bias[col];
#pragma unroll
        for (int r = 0; r < 4; ++r)
          Of[(size_t)(row + r) * 1024 + col] = acc[i][j][r] + bv;
      }
    }
  } else {
    const int sel = n0 >> 10;  // 0=Q 1=K 2=V (uniform per block)
#pragma unroll
    for (int i = 0; i < 4; ++i) {
      int row = m0 + wr + i * 16 + g * 4;
      int b = row >> 11, s = row & 2047;
#pragma unroll
      for (int j = 0; j < 4; ++j) {
        int col = n0 + wc + j * 16 + lr;
        float bv = bias[col];
        int nn = col & 1023;
        int h = nn >> 6, hd = nn & 63;
        if (sel == 2) {  // V -> transposed [bh][hd][s], 4 consecutive s per lane
          u16 pk[4];
#pragma unroll
          for (int r = 0; r < 4; ++r) pk[r] = f2bf(acc[i][j][r] + bv);
          uint2 pv;
          pv.x = (u32)pk[0] | ((u32)pk[1] << 16);
          pv.y = (u32)pk[2] | ((u32)pk[3] << 16);
          *(uint2*)(Vt + (size_t)((b * 16 + h) * 64 + hd) * 2048 + s) = pv;
        } else {
          u16* dst = (sel == 0) ? Qo : Ko;
#pragma unroll
          for (int r = 0; r < 4; ++r)
            dst[(size_t)((b * 16 + h) * 2048 + s + r) * 64 + hd] =
                f2bf(acc[i][j][r] + bv);
        }
      }
    }
  }
}

// ---------------- flash attention: 1 wave/block, K/V direct from global ----
// grid 2048 flat, XCD-swizzled: logical = (p&7)*256 + p>>3 -> each XCD owns
// 4 bh (K+V = 2MB, L2-resident); one K/V row = 128B = one cache line, so a
// wave's 8 chunk-reads/tile hit the same lines (L1 reuse).
// Wave owns 32 q-rows. Swapped QK^T (A=K,B=Q), both operands read with the
// same claimed contiguous-8 k-layout -> true-layout permutation cancels.
// C/D (verified): col=lane&31 (=q), row=(reg&3)+8*(reg>>2)+4*(lane>>5) (=kv).
// PV routes P through a wave-private LDS tile at TRUE kv coords (A-frag and
// V B-frag read with the same claim -> cancels; correct for any bijection).
__global__ __launch_bounds__(64, 2) void attn_k(const u16* __restrict__ Q,
                                                const u16* __restrict__ K,
                                                const u16* __restrict__ Vt,
                                                u16* __restrict__ O) {
  __shared__ alignas(16) u32 Ps[32 * 32];  // [q=32][kv-word=32], XOR-swizzled
  const int lane = threadIdx.x & 63;
  const int l31 = lane & 31, b5 = lane >> 5;
  const int p = blockIdx.x;
  const int logical = (p & 7) * 256 + (p >> 3);  // XCD chunking (2048 % 8 == 0)
  const int qt = logical & 63;
  const int bh = logical >> 6;
  const u16* Qh = Q + (size_t)bh * 2048 * 64;
  const u16* Kh = K + (size_t)bh * 2048 * 64;
  const u16* Vh = Vt + (size_t)bh * 64 * 2048;

  // Q B-frags (registers, constant over kv tiles): col q = qbase+l31
  const int qbase = qt * 32;
  const u16* qp = Qh + (size_t)(qbase + l31) * 64 + b5 * 8;
  bf16x8 qf[4];
#pragma unroll
  for (int c = 0; c < 4; ++c) qf[c] = *(const bf16x8*)(qp + 16 * c);

  u32* pw = Ps + l31 * 32;
  const int swz = (l31 & 7) << 2;

  f32x16 accO0, accO1;
#pragma unroll
  for (int r = 0; r < 16; ++r) { accO0[r] = 0.f; accO1[r] = 0.f; }
  float mraw = -1e30f;  // running max for q=l31 (raw-score units)
  float mC = 0.f;       // mraw * C2 (exp2 domain)
  float lsum = 0.f;     // per-lane partial denominator

  const float C2 = 0.125f * 1.44269504088896f;  // SCALE * log2(e)

  // software pipeline: K frags for tile 0
  bf16x8 k0[4], k1[4];
#pragma unroll
  for (int c = 0; c < 4; ++c) {
    k0[c] = *(const bf16x8*)(Kh + (size_t)l31 * 64 + (2 * c + b5) * 8);
    k1[c] = *(const bf16x8*)(Kh + (size_t)(32 + l31) * 64 + (2 * c + b5) * 8);
  }

#pragma unroll 2
  for (int t = 0; t < 32; ++t) {
    const int kv0 = t * 64;
    // V frags for this tile: issue now, consumed after softmax (~300cy cover)
    bf16x8 v0[4], v1[4];
#pragma unroll
    for (int c = 0; c < 4; ++c) {
      v0[c] = *(const bf16x8*)(Vh + (size_t)l31 * 2048 + kv0 + (2 * c + b5) * 8);
      v1[c] = *(const bf16x8*)(Vh + (size_t)(32 + l31) * 2048 + kv0 + (2 * c + b5) * 8);
    }

    // QK^T swapped (A=K, B=Q)
    f32x16 s0, s1;
#pragma unroll
    for (int r = 0; r < 16; ++r) { s0[r] = 0.f; s1[r] = 0.f; }
    __builtin_amdgcn_s_setprio(1);
#pragma unroll
    for (int c = 0; c < 4; ++c) {
      s0 = MFMA32(k0[c], qf[c], s0);
      s1 = MFMA32(k1[c], qf[c], s1);
    }
    __builtin_amdgcn_s_setprio(0);

    // prefetch next tile's K frags (latency hidden under softmax + PV)
    if (t < 31) {
      const int kvn = kv0 + 64;
#pragma unroll
      for (int c = 0; c < 4; ++c) {
        k0[c] = *(const bf16x8*)(Kh + (size_t)(kvn + l31) * 64 + (2 * c + b5) * 8);
        k1[c] = *(const bf16x8*)(Kh + (size_t)(kvn + 32 + l31) * 64 + (2 * c + b5) * 8);
      }
    }

    // lane-local max over this lane's 32 kv values (q = l31)
    float rmax;
    {
      float a0 = fmaxf(fmaxf(s0[0], s0[1]), fmaxf(s0[2], s0[3]));
      float a1 = fmaxf(fmaxf(s0[4], s0[5]), fmaxf(s0[6], s0[7]));
      float a2 = fmaxf(fmaxf(s0[8], s0[9]), fmaxf(s0[10], s0[11]));
      float a3 = fmaxf(fmaxf(s0[12], s0[13]), fmaxf(s0[14], s0[15]));
      float b0 = fmaxf(fmaxf(s1[0], s1[1]), fmaxf(s1[2], s1[3]));
      float b1 = fmaxf(fmaxf(s1[4], s1[5]), fmaxf(s1[6], s1[7]));
      float b2 = fmaxf(fmaxf(s1[8], s1[9]), fmaxf(s1[10], s1[11]));
      float b3 = fmaxf(fmaxf(s1[12], s1[13]), fmaxf(s1[14], s1[15]));
      rmax = fmaxf(fmaxf(fmaxf(a0, a1), fmaxf(a2, a3)),
                   fmaxf(fmaxf(b0, b1), fmaxf(b2, b3)));
    }
    rmax = fmaxf(rmax, __shfl_xor(rmax, 32));  // combine the two kv-subsets

    // defer-max: only rescale when a row grew by > 8 (scaled) = 64 raw
    if (__any(rmax > mraw + 64.f)) {
      float mn = fmaxf(mraw, rmax);
      float al = EXP2((mraw - mn) * C2);
      mraw = mn;
      mC = mn * C2;
      lsum *= al;
#pragma unroll
      for (int r = 0; r < 16; ++r) {
        float ar = __shfl(al, (r & 3) + 8 * (r >> 2) + 4 * b5);
        accO0[r] *= ar;
        accO1[r] *= ar;
      }
    }

    // P = exp2(s*C2 - mC); pack reg-adjacent (=kv-adjacent) pairs; write to
    // wave-private P tile at TRUE kv coords (words (i&1)+4*(i>>1)+2*b5; +16 s1)
    u32 w0[8], w1[8];
#pragma unroll
    for (int i = 0; i < 8; ++i) {
      float p0 = EXP2(__builtin_fmaf(s0[2 * i], C2, -mC));
      float p1 = EXP2(__builtin_fmaf(s0[2 * i + 1], C2, -mC));
      float p2 = EXP2(__builtin_fmaf(s1[2 * i], C2, -mC));
      float p3 = EXP2(__builtin_fmaf(s1[2 * i + 1], C2, -mC));
      lsum += (p0 + p1) + (p2 + p3);
      w0[i] = cvtpk(p0, p1);
      w1[i] = cvtpk(p2, p3);
    }
#pragma unroll
    for (int j = 0; j < 4; ++j) {
      uint2 a; a.x = w0[2 * j]; a.y = w0[2 * j + 1];
      uint2 b; b.x = w1[2 * j]; b.y = w1[2 * j + 1];
      *(uint2*)(pw + ((4 * j + 2 * b5) ^ swz)) = a;        // kv words 4j+2b5,+1
      *(uint2*)(pw + ((16 + 4 * j + 2 * b5) ^ swz)) = b;   // s1 half
    }

    // PV: A-frag (P from LDS) and B-frag (V) read with the same claimed
    // contiguous-8 layout -> cancels. Chunk c covers kv 16c..16c+15.
    __builtin_amdgcn_s_setprio(1);
#pragma unroll
    for (int c = 0; c < 4; ++c) {
      bf16x8 pf = *(const bf16x8*)(pw + ((8 * c + 4 * b5) ^ swz));
      accO0 = MFMA32(pf, v0[c], accO0);
      accO1 = MFMA32(pf, v1[c], accO1);
    }
    __builtin_amdgcn_s_setprio(0);
  }

  // finish: combine half-lane partial denominators, broadcast 1/l per row
  float ls = lsum + __shfl_xor(lsum, 32);
  float inv = 1.f / ls;
  const int b = bh >> 4, h = bh & 15;
#pragma unroll
  for (int r = 0; r < 16; ++r) {
    float ir = __shfl(inv, (r & 3) + 8 * (r >> 2) + 4 * b5);
    int qr = qbase + (r & 3) + 8 * (r >> 2) + 4 * b5;
    size_t rowoff = (size_t)(b * 2048 + qr) * 1024 + h * 64;
    O[rowoff + l31] = f2bf(accO0[r] * ir);
    O[rowoff + 32 + l31] = f2bf(accO1[r] * ir);
  }
}

extern "C" void kernel_launch(void* const* d_in, const int* in_sizes, int n_in,
                              void* d_out, int out_size, void* d_ws, size_t ws_size,
                              hipStream_t stream) {
  (void)in_sizes; (void)n_in; (void)out_size; (void)ws_size;
  const float* x = (const float*)d_in[0];
  const float* Wqkv = (const float*)d_in[1];
  const float* bqkv = (const float*)d_in[2];
  const float* Wproj = (const float*)d_in[3];
  const float* bproj = (const float*)d_in[4];
  float* out = (float*)d_out;

  char* ws = (char*)d_ws;
  size_t off = 0;
  auto alloc = [&](size_t bytes) {
    void* p = ws + off;
    off += (bytes + 255) & ~(size_t)255;
    return p;
  };
  u16* xb     = (u16*)alloc((size_t)4096 * 1024 * 2);
  u16* Wqkvt  = (u16*)alloc((size_t)3072 * 1024 * 2);
  u16* Wprojt = (u16*)alloc((size_t)1024 * 1024 * 2);
  u16* Qb     = (u16*)alloc((size_t)32 * 2048 * 64 * 2);
  u16* Kb     = (u16*)alloc((size_t)32 * 2048 * 64 * 2);
  u16* Vtb    = (u16*)alloc((size_t)32 * 64 * 2048 * 2);
  u16* AOb    = (u16*)alloc((size_t)4096 * 1024 * 2);

  convert_x<<<2048, 256, 0, stream>>>(x, xb, 4096 * 1024 / 4);
  transpose_w<<<dim3(96, 32), 256, 0, stream>>>(Wqkv, Wqkvt, 1024, 3072);
  transpose_w<<<dim3(32, 32), 256, 0, stream>>>(Wproj, Wprojt, 1024, 1024);
  gemm_k<0><<<dim3(24, 32), 256, 0, stream>>>(xb, Wqkvt, bqkv, Qb, Kb, Vtb, nullptr);
  attn_k<<<2048, 64, 0, stream>>>(Qb, Kb, Vtb, AOb);
  gemm_k<1><<<dim3(8, 32), 256, 0, stream>>>(AOb, Wprojt, bproj, nullptr, nullptr, nullptr, out);
}

// Round 8
// 156.740 us; speedup vs baseline: 1.3306x; 1.3306x over previous
//
#include <hip/hip_runtime.h>

typedef __attribute__((ext_vector_type(8))) short bf16x8;
typedef __attribute__((ext_vector_type(4))) float f32x4;
typedef __attribute__((ext_vector_type(16))) float f32x16;
typedef unsigned short u16;
typedef unsigned int u32;

#define MFMA16(a,b,c) __builtin_amdgcn_mfma_f32_16x16x32_bf16((a),(b),(c),0,0,0)
#define MFMA32(a,b,c) __builtin_amdgcn_mfma_f32_32x32x16_bf16((a),(b),(c),0,0,0)

#if __has_builtin(__builtin_amdgcn_exp2f)
#define EXP2(x) __builtin_amdgcn_exp2f(x)
#else
#define EXP2(x) __expf((x) * 0.6931471805599453f)
#endif

// f32 -> bf16 round-to-nearest-even
__device__ __forceinline__ u16 f2bf(float f) {
  u32 u = __builtin_bit_cast(u32, f);
  u += 0x7FFFu + ((u >> 16) & 1u);
  return (u16)(u >> 16);
}

// packed pair f32x2 -> bf16x2 (RNE) in one instruction
__device__ __forceinline__ u32 cvtpk(float lo, float hi) {
  u32 r;
  asm("v_cvt_pk_bf16_f32 %0, %1, %2" : "=v"(r) : "v"(lo), "v"(hi));
  return r;
}

// async 16B global -> LDS (dest must be wave-uniform base + lane*16)
__device__ __forceinline__ void gload16(const u16* g, u16* l) {
  __builtin_amdgcn_global_load_lds(
      (const __attribute__((address_space(1))) u32*)(const void*)g,
      (__attribute__((address_space(3))) u32*)(void*)l, 16, 0, 0);
}

// swizzled 16B fragment read from a [R][64] bf16 LDS tile (chunk = 8-elem unit)
__device__ __forceinline__ bf16x8 ldsfrag(const u16* lds, int row, int chunk) {
  return *(const bf16x8*)(lds + row * 64 + ((chunk ^ (row & 7)) << 3));
}

// ---------------- x f32 -> bf16 ----------------
__global__ __launch_bounds__(256) void convert_x(const float* __restrict__ in,
                                                 u16* __restrict__ out, int n4) {
  int i = blockIdx.x * blockDim.x + threadIdx.x;
  int stride = gridDim.x * blockDim.x;
  for (; i < n4; i += stride) {
    float4 v = ((const float4*)in)[i];
    u32 lo = (u32)f2bf(v.x) | ((u32)f2bf(v.y) << 16);
    u32 hi = (u32)f2bf(v.z) | ((u32)f2bf(v.w) << 16);
    uint2 pv; pv.x = lo; pv.y = hi;
    ((uint2*)out)[i] = pv;
  }
}

// ---------------- W [R][C] f32 -> Wt [C][R] bf16 (R = 1024) ----------------
__global__ __launch_bounds__(256) void transpose_w(const float* __restrict__ in,
                                                   u16* __restrict__ out,
                                                   int R, int C) {
  __shared__ float t[32][33];
  int c0 = blockIdx.x * 32, r0 = blockIdx.y * 32;
  int tc = threadIdx.x & 31, tr = threadIdx.x >> 5;  // tr in 0..7
#pragma unroll
  for (int j = 0; j < 4; ++j) {
    int r = tr + j * 8;
    t[r][tc] = in[(size_t)(r0 + r) * C + c0 + tc];
  }
  __syncthreads();
#pragma unroll
  for (int j = 0; j < 4; ++j) {
    int cc = tr + j * 8;
    out[(size_t)(c0 + cc) * R + r0 + tc] = f2bf(t[tc][cc]);
  }
}

// ---------------- GEMM: C[M,n] = A[M,1024] * Bt[n,1024]^T + bias ----------------
// MODE 0: qkv with scatter epilogue -> Q,K [bh][2048][64], V transposed [bh][64][2048]
// MODE 1: f32 output [M][1024]
template <int MODE>
__global__ __launch_bounds__(256) void gemm_k(
    const u16* __restrict__ A, const u16* __restrict__ Bt,
    const float* __restrict__ bias,
    u16* __restrict__ Qo, u16* __restrict__ Ko, u16* __restrict__ Vt,
    float* __restrict__ Of) {
  __shared__ alignas(16) u16 As[128 * 32];
  __shared__ alignas(16) u16 Bs[128 * 32];
  const int tid = threadIdx.x;
  const int wid = tid >> 6, lane = tid & 63;
  const int g = lane >> 4, lr = lane & 15;
  const int m0 = blockIdx.y * 128, n0 = blockIdx.x * 128;
  const int wr = (wid >> 1) * 64, wc = (wid & 1) * 64;

  f32x4 acc[4][4];
#pragma unroll
  for (int i = 0; i < 4; ++i)
#pragma unroll
    for (int j = 0; j < 4; ++j) acc[i][j] = (f32x4){0.f, 0.f, 0.f, 0.f};

  const u16* Ab = A + (size_t)m0 * 1024;
  const u16* Bb = Bt + (size_t)n0 * 1024;

  for (int kt = 0; kt < 1024; kt += 32) {
#pragma unroll
    for (int i = 0; i < 2; ++i) {
      int s = tid + i * 256;           // 16B chunk id, 512 per tile
      int row = s >> 2, c = s & 3;     // 4 chunks per 32-elem row
      gload16(Ab + row * 1024 + kt + c * 8, As + s * 8);
      gload16(Bb + row * 1024 + kt + c * 8, Bs + s * 8);
    }
    __syncthreads();
    bf16x8 af[4], bfr[4];
#pragma unroll
    for (int i = 0; i < 4; ++i)
      af[i] = *(const bf16x8*)(As + (wr + i * 16 + lr) * 32 + g * 8);
#pragma unroll
    for (int j = 0; j < 4; ++j)
      bfr[j] = *(const bf16x8*)(Bs + (wc + j * 16 + lr) * 32 + g * 8);
    __builtin_amdgcn_s_setprio(1);
#pragma unroll
    for (int i = 0; i < 4; ++i)
#pragma unroll
      for (int j = 0; j < 4; ++j)
        acc[i][j] = MFMA16(af[i], bfr[j], acc[i][j]);
    __builtin_amdgcn_s_setprio(0);
    __syncthreads();
  }

  if constexpr (MODE == 1) {
#pragma unroll
    for (int i = 0; i < 4; ++i) {
      int row = m0 + wr + i * 16 + g * 4;
#pragma unroll
      for (int j = 0; j < 4; ++j) {
        int col = n0 + wc + j * 16 + lr;
        float bv = bias[col];
#pragma unroll
        for (int r = 0; r < 4; ++r)
          Of[(size_t)(row + r) * 1024 + col] = acc[i][j][r] + bv;
      }
    }
  } else {
    const int sel = n0 >> 10;  // 0=Q 1=K 2=V (uniform per block)
#pragma unroll
    for (int i = 0; i < 4; ++i) {
      int row = m0 + wr + i * 16 + g * 4;
      int b = row >> 11, s = row & 2047;
#pragma unroll
      for (int j = 0; j < 4; ++j) {
        int col = n0 + wc + j * 16 + lr;
        float bv = bias[col];
        int nn = col & 1023;
        int h = nn >> 6, hd = nn & 63;
        if (sel == 2) {  // V -> transposed [bh][hd][s], 4 consecutive s per lane
          u16 pk[4];
#pragma unroll
          for (int r = 0; r < 4; ++r) pk[r] = f2bf(acc[i][j][r] + bv);
          uint2 pv;
          pv.x = (u32)pk[0] | ((u32)pk[1] << 16);
          pv.y = (u32)pk[2] | ((u32)pk[3] << 16);
          *(uint2*)(Vt + (size_t)((b * 16 + h) * 64 + hd) * 2048 + s) = pv;
        } else {
          u16* dst = (sel == 0) ? Qo : Ko;
#pragma unroll
          for (int r = 0; r < 4; ++r)
            dst[(size_t)((b * 16 + h) * 2048 + s + r) * 64 + hd] =
                f2bf(acc[i][j][r] + bv);
        }
      }
    }
  }
}

// ---------------- flash attention, split-KV: 32x32 MFMA, QBLK=32/wave ----
// grid (16 q-tiles of 128, 32 bh, 2 kv-splits); block 256 = 4 waves.
// Each block processes kv tiles [split*16, split*16+16), writing UNNORMALIZED
// partial O (f32) plus per-row (m, l) for the combine kernel.
// Swapped QK^T (A=K,B=Q), both operands read with the same claimed
// contiguous-8 k-layout -> true-layout permutation cancels. C/D (verified):
// col=lane&31 (=q), row=(reg&3)+8*(reg>>2)+4*(lane>>5) (=kv). PV routes P
// through a per-wave LDS tile at TRUE kv coords (cancellation-safe).
__global__ __launch_bounds__(256, 3) void attn_k(const u16* __restrict__ Q,
                                                 const u16* __restrict__ K,
                                                 const u16* __restrict__ Vt,
                                                 float* __restrict__ Op,
                                                 float2* __restrict__ Ml) {
  __shared__ alignas(16) u16 Ks[2 * 64 * 64];   // [buf][kv][hd], chunk-XOR swizzled
  __shared__ alignas(16) u16 Vs[2 * 64 * 64];   // [buf][hd][kv], chunk-XOR swizzled
  __shared__ alignas(16) u32 Ps[4 * 32 * 32];   // per-wave [q=32][kv-word=32], swizzled
  const int tid = threadIdx.x;
  const int wid = tid >> 6, lane = tid & 63;
  const int l31 = lane & 31, b5 = lane >> 5;
  const int bh = blockIdx.y;
  const int split = blockIdx.z;
  const int kvbase = split * 1024;
  const u16* Qh = Q + (size_t)bh * 2048 * 64;
  const u16* Kh = K + (size_t)bh * 2048 * 64;
  const u16* Vh = Vt + (size_t)bh * 64 * 2048;

  // stage K/V tile (kvbase) into buf 0 (async)
#pragma unroll
  for (int i = 0; i < 2; ++i) {
    int s = tid + i * 256;
    int row = s >> 3, c = (s & 7) ^ (row & 7);
    gload16(Kh + (kvbase + row) * 64 + c * 8, Ks + s * 8);
    gload16(Vh + row * 2048 + kvbase + c * 8, Vs + s * 8);
  }

  // Q B-frags (registers, constant over kv tiles): col q = qbase+l31
  const int qbase = blockIdx.x * 128 + wid * 32;
  const u16* qp = Qh + (size_t)(qbase + l31) * 64 + b5 * 8;
  bf16x8 qf[4];
#pragma unroll
  for (int c = 0; c < 4; ++c) qf[c] = *(const bf16x8*)(qp + 16 * c);
  __syncthreads();  // drains tile-0 staging

  u32* pw = Ps + wid * 1024 + l31 * 32;
  const int swz = (l31 & 7) << 2;

  f32x16 accO0, accO1;
#pragma unroll
  for (int r = 0; r < 16; ++r) { accO0[r] = 0.f; accO1[r] = 0.f; }
  float mraw = -1e30f;  // running max for q=l31 (raw-score units)
  float mC = 0.f;       // mraw * C2 (exp2 domain)
  float lsum = 0.f;     // per-lane partial denominator

  const float C2 = 0.125f * 1.44269504088896f;  // SCALE * log2(e)

  for (int t = 0; t < 16; ++t) {
    const u16* Kc = Ks + (t & 1) * 4096;
    const u16* Vc = Vs + (t & 1) * 4096;
    // issue next tile's staging before compute (hidden under MFMA+softmax)
    if (t < 15) {
      int kvn = kvbase + (t + 1) * 64;
      u16* Kn = Ks + ((t + 1) & 1) * 4096;
      u16* Vn = Vs + ((t + 1) & 1) * 4096;
#pragma unroll
      for (int i = 0; i < 2; ++i) {
        int s = tid + i * 256;
        int row = s >> 3, c = (s & 7) ^ (row & 7);
        gload16(Kh + (kvn + row) * 64 + c * 8, Kn + s * 8);
        gload16(Vh + row * 2048 + kvn + c * 8, Vn + s * 8);
      }
    }

    // QK^T swapped (A=K, B=Q): same claimed layout on both operands.
    f32x16 s0, s1;
#pragma unroll
    for (int r = 0; r < 16; ++r) { s0[r] = 0.f; s1[r] = 0.f; }
    __builtin_amdgcn_s_setprio(1);
#pragma unroll
    for (int c = 0; c < 4; ++c) {
      bf16x8 k0 = ldsfrag(Kc, l31, 2 * c + b5);
      bf16x8 k1 = ldsfrag(Kc, 32 + l31, 2 * c + b5);
      s0 = MFMA32(k0, qf[c], s0);
      s1 = MFMA32(k1, qf[c], s1);
    }
    __builtin_amdgcn_s_setprio(0);

    // lane-local max over this lane's 32 kv values (q = l31)
    float rmax;
    {
      float a0 = fmaxf(fmaxf(s0[0], s0[1]), fmaxf(s0[2], s0[3]));
      float a1 = fmaxf(fmaxf(s0[4], s0[5]), fmaxf(s0[6], s0[7]));
      float a2 = fmaxf(fmaxf(s0[8], s0[9]), fmaxf(s0[10], s0[11]));
      float a3 = fmaxf(fmaxf(s0[12], s0[13]), fmaxf(s0[14], s0[15]));
      float b0 = fmaxf(fmaxf(s1[0], s1[1]), fmaxf(s1[2], s1[3]));
      float b1 = fmaxf(fmaxf(s1[4], s1[5]), fmaxf(s1[6], s1[7]));
      float b2 = fmaxf(fmaxf(s1[8], s1[9]), fmaxf(s1[10], s1[11]));
      float b3 = fmaxf(fmaxf(s1[12], s1[13]), fmaxf(s1[14], s1[15]));
      rmax = fmaxf(fmaxf(fmaxf(a0, a1), fmaxf(a2, a3)),
                   fmaxf(fmaxf(b0, b1), fmaxf(b2, b3)));
    }
    rmax = fmaxf(rmax, __shfl_xor(rmax, 32));  // combine the two kv-subsets

    // defer-max: only rescale when a row grew by > 8 (scaled) = 64 raw
    if (__any(rmax > mraw + 64.f)) {
      float mn = fmaxf(mraw, rmax);
      float al = EXP2((mraw - mn) * C2);
      mraw = mn;
      mC = mn * C2;
      lsum *= al;
#pragma unroll
      for (int r = 0; r < 16; ++r) {
        float ar = __shfl(al, (r & 3) + 8 * (r >> 2) + 4 * b5);
        accO0[r] *= ar;
        accO1[r] *= ar;
      }
    }

    // P = exp2(s*C2 - mC); pack reg-adjacent (=kv-adjacent) pairs; write to
    // per-wave P tile at TRUE kv coords (words (i&1)+4*(i>>1)+2*b5; +16 s1)
    u32 w0[8], w1[8];
#pragma unroll
    for (int i = 0; i < 8; ++i) {
      float p0 = EXP2(__builtin_fmaf(s0[2 * i], C2, -mC));
      float p1 = EXP2(__builtin_fmaf(s0[2 * i + 1], C2, -mC));
      float p2 = EXP2(__builtin_fmaf(s1[2 * i], C2, -mC));
      float p3 = EXP2(__builtin_fmaf(s1[2 * i + 1], C2, -mC));
      lsum += (p0 + p1) + (p2 + p3);
      w0[i] = cvtpk(p0, p1);
      w1[i] = cvtpk(p2, p3);
    }
#pragma unroll
    for (int j = 0; j < 4; ++j) {
      uint2 a; a.x = w0[2 * j]; a.y = w0[2 * j + 1];
      uint2 b; b.x = w1[2 * j]; b.y = w1[2 * j + 1];
      *(uint2*)(pw + ((4 * j + 2 * b5) ^ swz)) = a;        // kv words 4j+2b5,+1
      *(uint2*)(pw + ((16 + 4 * j + 2 * b5) ^ swz)) = b;   // s1 half
    }

    // PV: A-frag (P) and B-frag (V) both read with claimed contiguous-8 ->
    // cancels. Chunk c covers kv 16c..16c+15.
    __builtin_amdgcn_s_setprio(1);
#pragma unroll
    for (int c = 0; c < 4; ++c) {
      bf16x8 pf = *(const bf16x8*)(pw + ((8 * c + 4 * b5) ^ swz));
      bf16x8 v0 = ldsfrag(Vc, l31, 2 * c + b5);
      bf16x8 v1 = ldsfrag(Vc, 32 + l31, 2 * c + b5);
      accO0 = MFMA32(pf, v0, accO0);
      accO1 = MFMA32(pf, v1, accO1);
    }
    __builtin_amdgcn_s_setprio(0);
    __syncthreads();  // single barrier: buffer handoff + drain of next-tile loads
  }

  // epilogue: store UNNORMALIZED partial O (f32) + per-row (m, l)
  float ls = lsum + __shfl_xor(lsum, 32);
  if (b5 == 0)
    Ml[(size_t)split * 65536 + bh * 2048 + qbase + l31] = make_float2(mraw, ls);
  float* ob = Op + ((size_t)split * 65536 + bh * 2048) * 64;
#pragma unroll
  for (int r = 0; r < 16; ++r) {
    int qr = qbase + (r & 3) + 8 * (r >> 2) + 4 * b5;
    ob[(size_t)qr * 64 + l31] = accO0[r];
    ob[(size_t)qr * 64 + 32 + l31] = accO1[r];
  }
}

// ---------------- split-KV combine: merge 2 partials, write bf16 [b][s][h*64+d]
__global__ __launch_bounds__(256) void combine_k(const float* __restrict__ Op,
                                                 const float2* __restrict__ Ml,
                                                 u16* __restrict__ O) {
  const float C2 = 0.125f * 1.44269504088896f;
  int idx = blockIdx.x * blockDim.x + threadIdx.x;  // 65536 rows * 16 groups
  int row = idx >> 4, d0 = (idx & 15) * 4;
  float2 ml1 = Ml[row];
  float2 ml2 = Ml[65536 + row];
  float ms = fmaxf(ml1.x, ml2.x);
  float w1 = EXP2((ml1.x - ms) * C2);
  float w2 = EXP2((ml2.x - ms) * C2);
  float inv = 1.f / (w1 * ml1.y + w2 * ml2.y);
  float4 o1 = *(const float4*)(Op + (size_t)row * 64 + d0);
  float4 o2 = *(const float4*)(Op + (size_t)65536 * 64 + (size_t)row * 64 + d0);
  int bh = row >> 11, q = row & 2047;
  int b = bh >> 4, h = bh & 15;
  u16* dst = O + (size_t)(b * 2048 + q) * 1024 + h * 64 + d0;
  uint2 pv;
  pv.x = (u32)f2bf((o1.x * w1 + o2.x * w2) * inv) |
         ((u32)f2bf((o1.y * w1 + o2.y * w2) * inv) << 16);
  pv.y = (u32)f2bf((o1.z * w1 + o2.z * w2) * inv) |
         ((u32)f2bf((o1.w * w1 + o2.w * w2) * inv) << 16);
  *(uint2*)dst = pv;
}

extern "C" void kernel_launch(void* const* d_in, const int* in_sizes, int n_in,
                              void* d_out, int out_size, void* d_ws, size_t ws_size,
                              hipStream_t stream) {
  (void)in_sizes; (void)n_in; (void)out_size; (void)ws_size;
  const float* x = (const float*)d_in[0];
  const float* Wqkv = (const float*)d_in[1];
  const float* bqkv = (const float*)d_in[2];
  const float* Wproj = (const float*)d_in[3];
  const float* bproj = (const float*)d_in[4];
  float* out = (float*)d_out;

  char* ws = (char*)d_ws;
  size_t off = 0;
  auto alloc = [&](size_t bytes) {
    void* p = ws + off;
    off += (bytes + 255) & ~(size_t)255;
    return p;
  };
  u16* xb     = (u16*)alloc((size_t)4096 * 1024 * 2);
  u16* Wqkvt  = (u16*)alloc((size_t)3072 * 1024 * 2);
  u16* Wprojt = (u16*)alloc((size_t)1024 * 1024 * 2);
  u16* Qb     = (u16*)alloc((size_t)32 * 2048 * 64 * 2);
  u16* Kb     = (u16*)alloc((size_t)32 * 2048 * 64 * 2);
  u16* Vtb    = (u16*)alloc((size_t)32 * 64 * 2048 * 2);
  u16* AOb    = (u16*)alloc((size_t)4096 * 1024 * 2);
  float*  Opart = (float*)alloc((size_t)2 * 65536 * 64 * 4);
  float2* Mlp   = (float2*)alloc((size_t)2 * 65536 * 8);

  convert_x<<<2048, 256, 0, stream>>>(x, xb, 4096 * 1024 / 4);
  transpose_w<<<dim3(96, 32), 256, 0, stream>>>(Wqkv, Wqkvt, 1024, 3072);
  transpose_w<<<dim3(32, 32), 256, 0, stream>>>(Wproj, Wprojt, 1024, 1024);
  gemm_k<0><<<dim3(24, 32), 256, 0, stream>>>(xb, Wqkvt, bqkv, Qb, Kb, Vtb, nullptr);
  attn_k<<<dim3(16, 32, 2), 256, 0, stream>>>(Qb, Kb, Vtb, Opart, Mlp);
  combine_k<<<4096, 256, 0, stream>>>(Opart, Mlp, AOb);
  gemm_k<1><<<dim3(8, 32), 256, 0, stream>>>(AOb, Wprojt, bproj, nullptr, nullptr, nullptr, out);
}

// Round 9
// 132.943 us; speedup vs baseline: 1.5688x; 1.1790x over previous
//
#include <hip/hip_runtime.h>

typedef __attribute__((ext_vector_type(8))) short bf16x8;
typedef __attribute__((ext_vector_type(4))) float f32x4;
typedef __attribute__((ext_vector_type(16))) float f32x16;
typedef unsigned short u16;
typedef unsigned int u32;

#define MFMA16(a,b,c) __builtin_amdgcn_mfma_f32_16x16x32_bf16((a),(b),(c),0,0,0)
#define MFMA32(a,b,c) __builtin_amdgcn_mfma_f32_32x32x16_bf16((a),(b),(c),0,0,0)

#if __has_builtin(__builtin_amdgcn_exp2f)
#define EXP2(x) __builtin_amdgcn_exp2f(x)
#else
#define EXP2(x) __expf((x) * 0.6931471805599453f)
#endif

// f32 -> bf16 round-to-nearest-even
__device__ __forceinline__ u16 f2bf(float f) {
  u32 u = __builtin_bit_cast(u32, f);
  u += 0x7FFFu + ((u >> 16) & 1u);
  return (u16)(u >> 16);
}

// packed pair f32x2 -> bf16x2 (RNE) in one instruction
__device__ __forceinline__ u32 cvtpk(float lo, float hi) {
  u32 r;
  asm("v_cvt_pk_bf16_f32 %0, %1, %2" : "=v"(r) : "v"(lo), "v"(hi));
  return r;
}

// async 16B global -> LDS (dest must be wave-uniform base + lane*16)
__device__ __forceinline__ void gload16(const u16* g, u16* l) {
  __builtin_amdgcn_global_load_lds(
      (const __attribute__((address_space(1))) u32*)(const void*)g,
      (__attribute__((address_space(3))) u32*)(void*)l, 16, 0, 0);
}

// swizzled 16B fragment read from a [R][64] bf16 LDS tile (chunk = 8-elem unit)
__device__ __forceinline__ bf16x8 ldsfrag(const u16* lds, int row, int chunk) {
  return *(const bf16x8*)(lds + row * 64 + ((chunk ^ (row & 7)) << 3));
}

// ---------------- x f32 -> bf16 ----------------
__global__ __launch_bounds__(256) void convert_x(const float* __restrict__ in,
                                                 u16* __restrict__ out, int n4) {
  int i = blockIdx.x * blockDim.x + threadIdx.x;
  int stride = gridDim.x * blockDim.x;
  for (; i < n4; i += stride) {
    float4 v = ((const float4*)in)[i];
    u32 lo = (u32)f2bf(v.x) | ((u32)f2bf(v.y) << 16);
    u32 hi = (u32)f2bf(v.z) | ((u32)f2bf(v.w) << 16);
    uint2 pv; pv.x = lo; pv.y = hi;
    ((uint2*)out)[i] = pv;
  }
}

// ---------------- W [R][C] f32 -> Wt [C][R] bf16 (R = 1024) ----------------
__global__ __launch_bounds__(256) void transpose_w(const float* __restrict__ in,
                                                   u16* __restrict__ out,
                                                   int R, int C) {
  __shared__ float t[32][33];
  int c0 = blockIdx.x * 32, r0 = blockIdx.y * 32;
  int tc = threadIdx.x & 31, tr = threadIdx.x >> 5;  // tr in 0..7
#pragma unroll
  for (int j = 0; j < 4; ++j) {
    int r = tr + j * 8;
    t[r][tc] = in[(size_t)(r0 + r) * C + c0 + tc];
  }
  __syncthreads();
#pragma unroll
  for (int j = 0; j < 4; ++j) {
    int cc = tr + j * 8;
    out[(size_t)(c0 + cc) * R + r0 + tc] = f2bf(t[tc][cc]);
  }
}

// ---------------- GEMM: C[M,n] = A[M,1024] * Bt[n,1024]^T + bias ----------------
// 2-phase double-buffered staging (T3-minimum): STAGE(t+1) issued BEFORE
// compute(t); ONE __syncthreads per K-step (its implicit vmcnt(0)+lgkmcnt(0)
// drain is the buffer handoff).
// MODE 0: qkv with scatter epilogue -> Q,K [bh][2048][64], V transposed [bh][64][2048]
// MODE 1: f32 output [M][1024]
template <int MODE>
__global__ __launch_bounds__(256) void gemm_k(
    const u16* __restrict__ A, const u16* __restrict__ Bt,
    const float* __restrict__ bias,
    u16* __restrict__ Qo, u16* __restrict__ Ko, u16* __restrict__ Vt,
    float* __restrict__ Of) {
  __shared__ alignas(16) u16 As[2][128 * 32];
  __shared__ alignas(16) u16 Bs[2][128 * 32];
  const int tid = threadIdx.x;
  const int wid = tid >> 6, lane = tid & 63;
  const int g = lane >> 4, lr = lane & 15;
  const int m0 = blockIdx.y * 128, n0 = blockIdx.x * 128;
  const int wr = (wid >> 1) * 64, wc = (wid & 1) * 64;

  f32x4 acc[4][4];
#pragma unroll
  for (int i = 0; i < 4; ++i)
#pragma unroll
    for (int j = 0; j < 4; ++j) acc[i][j] = (f32x4){0.f, 0.f, 0.f, 0.f};

  const u16* Ab = A + (size_t)m0 * 1024;
  const u16* Bb = Bt + (size_t)n0 * 1024;

  const int srow = tid >> 2, sc = tid & 3;          // staging coords (2 rounds)
  auto stage = [&](int buf, int kt) {
#pragma unroll
    for (int i = 0; i < 2; ++i) {
      int s = tid + i * 256;
      int row = srow + i * 64, c = sc;
      gload16(Ab + (size_t)row * 1024 + kt + c * 8, As[buf] + s * 8);
      gload16(Bb + (size_t)row * 1024 + kt + c * 8, Bs[buf] + s * 8);
    }
  };

  stage(0, 0);
  __syncthreads();  // tile 0 resident
  int cur = 0;
  for (int kt = 0; kt < 1024; kt += 32) {
    if (kt + 32 < 1024) stage(cur ^ 1, kt + 32);  // overlap with compute(t)
    bf16x8 af[4], bfr[4];
#pragma unroll
    for (int i = 0; i < 4; ++i)
      af[i] = *(const bf16x8*)(As[cur] + (wr + i * 16 + lr) * 32 + g * 8);
#pragma unroll
    for (int j = 0; j < 4; ++j)
      bfr[j] = *(const bf16x8*)(Bs[cur] + (wc + j * 16 + lr) * 32 + g * 8);
    __builtin_amdgcn_s_setprio(1);
#pragma unroll
    for (int i = 0; i < 4; ++i)
#pragma unroll
      for (int j = 0; j < 4; ++j)
        acc[i][j] = MFMA16(af[i], bfr[j], acc[i][j]);
    __builtin_amdgcn_s_setprio(0);
    __syncthreads();  // drain stage (vmcnt0) + all waves done reading buf[cur]
    cur ^= 1;
  }

  if constexpr (MODE == 1) {
#pragma unroll
    for (int i = 0; i < 4; ++i) {
      int row = m0 + wr + i * 16 + g * 4;
#pragma unroll
      for (int j = 0; j < 4; ++j) {
        int col = n0 + wc + j * 16 + lr;
        float bv = bias[col];
#pragma unroll
        for (int r = 0; r < 4; ++r)
          Of[(size_t)(row + r) * 1024 + col] = acc[i][j][r] + bv;
      }
    }
  } else {
    const int sel = n0 >> 10;  // 0=Q 1=K 2=V (uniform per block)
#pragma unroll
    for (int i = 0; i < 4; ++i) {
      int row = m0 + wr + i * 16 + g * 4;
      int b = row >> 11, s = row & 2047;
#pragma unroll
      for (int j = 0; j < 4; ++j) {
        int col = n0 + wc + j * 16 + lr;
        float bv = bias[col];
        int nn = col & 1023;
        int h = nn >> 6, hd = nn & 63;
        if (sel == 2) {  // V -> transposed [bh][hd][s], 4 consecutive s per lane
          u16 pk[4];
#pragma unroll
          for (int r = 0; r < 4; ++r) pk[r] = f2bf(acc[i][j][r] + bv);
          uint2 pv;
          pv.x = (u32)pk[0] | ((u32)pk[1] << 16);
          pv.y = (u32)pk[2] | ((u32)pk[3] << 16);
          *(uint2*)(Vt + (size_t)((b * 16 + h) * 64 + hd) * 2048 + s) = pv;
        } else {
          u16* dst = (sel == 0) ? Qo : Ko;
#pragma unroll
          for (int r = 0; r < 4; ++r)
            dst[(size_t)((b * 16 + h) * 2048 + s + r) * 64 + hd] =
                f2bf(acc[i][j][r] + bv);
        }
      }
    }
  }
}

// ---------------- flash attention: 32x32 MFMA, QBLK=32/wave, PV via LDS ----
// (R6 configuration — known-good at 69 µs.)
// grid (16 q-tiles of 128, 32 bh); block 256 = 4 waves; wave owns 32 q-rows.
// Swapped QK^T (A=K,B=Q), both operands read with the SAME claimed k-layout
// (contiguous-8) -> any true-layout permutation cancels. C/D layout (verified
// m74/m101): col=lane&31 (=q), row=(reg&3)+8*(reg>>2)+4*(lane>>5) (=kv).
// PV: P written to per-wave LDS tile at TRUE kv coords; A-frag and V B-frag
// both read with the same contiguous-8 claim -> cancels again.
__global__ __launch_bounds__(256, 2) void attn_k(const u16* __restrict__ Q,
                                                 const u16* __restrict__ K,
                                                 const u16* __restrict__ Vt,
                                                 u16* __restrict__ O) {
  __shared__ alignas(16) u16 Ks[2 * 64 * 64];   // [buf][kv][hd], chunk-XOR swizzled
  __shared__ alignas(16) u16 Vs[2 * 64 * 64];   // [buf][hd][kv], chunk-XOR swizzled
  __shared__ alignas(16) u32 Ps[4 * 32 * 32];   // per-wave [q=32][kv-word=32], swizzled
  const int tid = threadIdx.x;
  const int wid = tid >> 6, lane = tid & 63;
  const int l31 = lane & 31, b5 = lane >> 5;
  const int bh = blockIdx.y;
  const u16* Qh = Q + (size_t)bh * 2048 * 64;
  const u16* Kh = K + (size_t)bh * 2048 * 64;
  const u16* Vh = Vt + (size_t)bh * 64 * 2048;

  // stage K/V tile 0 into buf 0 (async)
#pragma unroll
  for (int i = 0; i < 2; ++i) {
    int s = tid + i * 256;
    int row = s >> 3, c = (s & 7) ^ (row & 7);
    gload16(Kh + row * 64 + c * 8, Ks + s * 8);
    gload16(Vh + row * 2048 + c * 8, Vs + s * 8);
  }

  // Q B-frags (registers, constant over kv tiles): col q = qbase+l31
  const int qbase = blockIdx.x * 128 + wid * 32;
  const u16* qp = Qh + (size_t)(qbase + l31) * 64 + b5 * 8;
  bf16x8 qf[4];
#pragma unroll
  for (int c = 0; c < 4; ++c) qf[c] = *(const bf16x8*)(qp + 16 * c);
  __syncthreads();  // drains tile-0 staging

  u32* pw = Ps + wid * 1024 + l31 * 32;
  const int swz = (l31 & 7) << 2;

  f32x16 accO0, accO1;
#pragma unroll
  for (int r = 0; r < 16; ++r) { accO0[r] = 0.f; accO1[r] = 0.f; }
  float mraw = -1e30f;  // running max for q=l31 (raw-score units)
  float mC = 0.f;       // mraw * C2 (exp2 domain)
  float lsum = 0.f;     // per-lane partial denominator

  const float C2 = 0.125f * 1.44269504088896f;  // SCALE * log2(e)

  for (int t = 0; t < 32; ++t) {
    const u16* Kc = Ks + (t & 1) * 4096;
    const u16* Vc = Vs + (t & 1) * 4096;
    // issue next tile's staging before compute (hidden under MFMA+softmax)
    if (t < 31) {
      int kvn = (t + 1) * 64;
      u16* Kn = Ks + ((t + 1) & 1) * 4096;
      u16* Vn = Vs + ((t + 1) & 1) * 4096;
#pragma unroll
      for (int i = 0; i < 2; ++i) {
        int s = tid + i * 256;
        int row = s >> 3, c = (s & 7) ^ (row & 7);
        gload16(Kh + (kvn + row) * 64 + c * 8, Kn + s * 8);
        gload16(Vh + row * 2048 + kvn + c * 8, Vn + s * 8);
      }
    }

    // QK^T swapped (A=K, B=Q): same claimed layout on both operands.
    f32x16 s0, s1;
#pragma unroll
    for (int r = 0; r < 16; ++r) { s0[r] = 0.f; s1[r] = 0.f; }
    __builtin_amdgcn_s_setprio(1);
#pragma unroll
    for (int c = 0; c < 4; ++c) {
      bf16x8 k0 = ldsfrag(Kc, l31, 2 * c + b5);
      bf16x8 k1 = ldsfrag(Kc, 32 + l31, 2 * c + b5);
      s0 = MFMA32(k0, qf[c], s0);
      s1 = MFMA32(k1, qf[c], s1);
    }
    __builtin_amdgcn_s_setprio(0);

    // lane-local max over this lane's 32 kv values (q = l31)
    float rmax;
    {
      float a0 = fmaxf(fmaxf(s0[0], s0[1]), fmaxf(s0[2], s0[3]));
      float a1 = fmaxf(fmaxf(s0[4], s0[5]), fmaxf(s0[6], s0[7]));
      float a2 = fmaxf(fmaxf(s0[8], s0[9]), fmaxf(s0[10], s0[11]));
      float a3 = fmaxf(fmaxf(s0[12], s0[13]), fmaxf(s0[14], s0[15]));
      float b0 = fmaxf(fmaxf(s1[0], s1[1]), fmaxf(s1[2], s1[3]));
      float b1 = fmaxf(fmaxf(s1[4], s1[5]), fmaxf(s1[6], s1[7]));
      float b2 = fmaxf(fmaxf(s1[8], s1[9]), fmaxf(s1[10], s1[11]));
      float b3 = fmaxf(fmaxf(s1[12], s1[13]), fmaxf(s1[14], s1[15]));
      rmax = fmaxf(fmaxf(fmaxf(a0, a1), fmaxf(a2, a3)),
                   fmaxf(fmaxf(b0, b1), fmaxf(b2, b3)));
    }
    rmax = fmaxf(rmax, __shfl_xor(rmax, 32));  // combine the two kv-subsets

    // defer-max: only rescale when a row grew by > 8 (scaled) = 64 raw
    if (__any(rmax > mraw + 64.f)) {
      float mn = fmaxf(mraw, rmax);
      float al = EXP2((mraw - mn) * C2);
      mraw = mn;
      mC = mn * C2;
      lsum *= al;
#pragma unroll
      for (int r = 0; r < 16; ++r) {
        float ar = __shfl(al, (r & 3) + 8 * (r >> 2) + 4 * b5);
        accO0[r] *= ar;
        accO1[r] *= ar;
      }
    }

    // P = exp2(s*C2 - mC); pack reg-adjacent (=kv-adjacent) pairs; write to
    // per-wave P tile at TRUE kv coords (words (i&1)+4*(i>>1)+2*b5; +16 s1)
    u32 w0[8], w1[8];
#pragma unroll
    for (int i = 0; i < 8; ++i) {
      float p0 = EXP2(__builtin_fmaf(s0[2 * i], C2, -mC));
      float p1 = EXP2(__builtin_fmaf(s0[2 * i + 1], C2, -mC));
      float p2 = EXP2(__builtin_fmaf(s1[2 * i], C2, -mC));
      float p3 = EXP2(__builtin_fmaf(s1[2 * i + 1], C2, -mC));
      lsum += (p0 + p1) + (p2 + p3);
      w0[i] = cvtpk(p0, p1);
      w1[i] = cvtpk(p2, p3);
    }
#pragma unroll
    for (int j = 0; j < 4; ++j) {
      uint2 a; a.x = w0[2 * j]; a.y = w0[2 * j + 1];
      uint2 b; b.x = w1[2 * j]; b.y = w1[2 * j + 1];
      *(uint2*)(pw + ((4 * j + 2 * b5) ^ swz)) = a;        // kv words 4j+2b5,+1
      *(uint2*)(pw + ((16 + 4 * j + 2 * b5) ^ swz)) = b;   // s1 half
    }

    // PV: A-frag (P) and B-frag (V) both read with claimed contiguous-8 ->
    // cancels. Chunk c covers kv 16c..16c+15.
    __builtin_amdgcn_s_setprio(1);
#pragma unroll
    for (int c = 0; c < 4; ++c) {
      bf16x8 pf = *(const bf16x8*)(pw + ((8 * c + 4 * b5) ^ swz));
      bf16x8 v0 = ldsfrag(Vc, l31, 2 * c + b5);
      bf16x8 v1 = ldsfrag(Vc, 32 + l31, 2 * c + b5);
      accO0 = MFMA32(pf, v0, accO0);
      accO1 = MFMA32(pf, v1, accO1);
    }
    __builtin_amdgcn_s_setprio(0);
    __syncthreads();  // single barrier: buffer handoff + drain of next-tile loads
  }

  // finish: combine half-lane partial denominators, broadcast 1/l per row
  float ls = lsum + __shfl_xor(lsum, 32);
  float inv = 1.f / ls;
  const int b = bh >> 4, h = bh & 15;
#pragma unroll
  for (int r = 0; r < 16; ++r) {
    float ir = __shfl(inv, (r & 3) + 8 * (r >> 2) + 4 * b5);
    int qr = qbase + (r & 3) + 8 * (r >> 2) + 4 * b5;
    size_t rowoff = (size_t)(b * 2048 + qr) * 1024 + h * 64;
    O[rowoff + l31] = f2bf(accO0[r] * ir);
    O[rowoff + 32 + l31] = f2bf(accO1[r] * ir);
  }
}

extern "C" void kernel_launch(void* const* d_in, const int* in_sizes, int n_in,
                              void* d_out, int out_size, void* d_ws, size_t ws_size,
                              hipStream_t stream) {
  (void)in_sizes; (void)n_in; (void)out_size; (void)ws_size;
  const float* x = (const float*)d_in[0];
  const float* Wqkv = (const float*)d_in[1];
  const float* bqkv = (const float*)d_in[2];
  const float* Wproj = (const float*)d_in[3];
  const float* bproj = (const float*)d_in[4];
  float* out = (float*)d_out;

  char* ws = (char*)d_ws;
  size_t off = 0;
  auto alloc = [&](size_t bytes) {
    void* p = ws + off;
    off += (bytes + 255) & ~(size_t)255;
    return p;
  };
  u16* xb     = (u16*)alloc((size_t)4096 * 1024 * 2);
  u16* Wqkvt  = (u16*)alloc((size_t)3072 * 1024 * 2);
  u16* Wprojt = (u16*)alloc((size_t)1024 * 1024 * 2);
  u16* Qb     = (u16*)alloc((size_t)32 * 2048 * 64 * 2);
  u16* Kb     = (u16*)alloc((size_t)32 * 2048 * 64 * 2);
  u16* Vtb    = (u16*)alloc((size_t)32 * 64 * 2048 * 2);
  u16* AOb    = (u16*)alloc((size_t)4096 * 1024 * 2);

  convert_x<<<2048, 256, 0, stream>>>(x, xb, 4096 * 1024 / 4);
  transpose_w<<<dim3(96, 32), 256, 0, stream>>>(Wqkv, Wqkvt, 1024, 3072);
  transpose_w<<<dim3(32, 32), 256, 0, stream>>>(Wproj, Wprojt, 1024, 1024);
  gemm_k<0><<<dim3(24, 32), 256, 0, stream>>>(xb, Wqkvt, bqkv, Qb, Kb, Vtb, nullptr);
  attn_k<<<dim3(16, 32), 256, 0, stream>>>(Qb, Kb, Vtb, AOb);
  gemm_k<1><<<dim3(8, 32), 256, 0, stream>>>(AOb, Wprojt, bproj, nullptr, nullptr, nullptr, out);
}

// Round 10
// 131.000 us; speedup vs baseline: 1.5921x; 1.0148x over previous
//
#include <hip/hip_runtime.h>

typedef __attribute__((ext_vector_type(8))) short bf16x8;
typedef __attribute__((ext_vector_type(4))) float f32x4;
typedef __attribute__((ext_vector_type(16))) float f32x16;
typedef unsigned short u16;
typedef unsigned int u32;

#define MFMA16(a,b,c) __builtin_amdgcn_mfma_f32_16x16x32_bf16((a),(b),(c),0,0,0)
#define MFMA32(a,b,c) __builtin_amdgcn_mfma_f32_32x32x16_bf16((a),(b),(c),0,0,0)

#if __has_builtin(__builtin_amdgcn_exp2f)
#define EXP2(x) __builtin_amdgcn_exp2f(x)
#else
#define EXP2(x) __expf((x) * 0.6931471805599453f)
#endif

// f32 -> bf16 round-to-nearest-even
__device__ __forceinline__ u16 f2bf(float f) {
  u32 u = __builtin_bit_cast(u32, f);
  u += 0x7FFFu + ((u >> 16) & 1u);
  return (u16)(u >> 16);
}

// packed pair f32x2 -> bf16x2 (RNE) in one instruction
__device__ __forceinline__ u32 cvtpk(float lo, float hi) {
  u32 r;
  asm("v_cvt_pk_bf16_f32 %0, %1, %2" : "=v"(r) : "v"(lo), "v"(hi));
  return r;
}

// async 16B global -> LDS (dest must be wave-uniform base + lane*16)
__device__ __forceinline__ void gload16(const u16* g, u16* l) {
  __builtin_amdgcn_global_load_lds(
      (const __attribute__((address_space(1))) u32*)(const void*)g,
      (__attribute__((address_space(3))) u32*)(void*)l, 16, 0, 0);
}

// swizzled 16B fragment read from a [R][64] bf16 LDS tile (chunk = 8-elem unit)
__device__ __forceinline__ bf16x8 ldsfrag(const u16* lds, int row, int chunk) {
  return *(const bf16x8*)(lds + row * 64 + ((chunk ^ (row & 7)) << 3));
}

// ---------------- x f32 -> bf16 ----------------
__global__ __launch_bounds__(256) void convert_x(const float* __restrict__ in,
                                                 u16* __restrict__ out, int n4) {
  int i = blockIdx.x * blockDim.x + threadIdx.x;
  int stride = gridDim.x * blockDim.x;
  for (; i < n4; i += stride) {
    float4 v = ((const float4*)in)[i];
    u32 lo = (u32)f2bf(v.x) | ((u32)f2bf(v.y) << 16);
    u32 hi = (u32)f2bf(v.z) | ((u32)f2bf(v.w) << 16);
    uint2 pv; pv.x = lo; pv.y = hi;
    ((uint2*)out)[i] = pv;
  }
}

// ---------------- W [R][C] f32 -> Wt [C][R] bf16 (R = 1024) ----------------
__global__ __launch_bounds__(256) void transpose_w(const float* __restrict__ in,
                                                   u16* __restrict__ out,
                                                   int R, int C) {
  __shared__ float t[32][33];
  int c0 = blockIdx.x * 32, r0 = blockIdx.y * 32;
  int tc = threadIdx.x & 31, tr = threadIdx.x >> 5;  // tr in 0..7
#pragma unroll
  for (int j = 0; j < 4; ++j) {
    int r = tr + j * 8;
    t[r][tc] = in[(size_t)(r0 + r) * C + c0 + tc];
  }
  __syncthreads();
#pragma unroll
  for (int j = 0; j < 4; ++j) {
    int cc = tr + j * 8;
    out[(size_t)(c0 + cc) * R + r0 + tc] = f2bf(t[tc][cc]);
  }
}

// ---------------- GEMM: C[M,n] = A[M,1024] * Bt[n,1024]^T + bias ----------------
// 2-phase double-buffered staging (T3-minimum): STAGE(t+1) issued BEFORE
// compute(t); ONE __syncthreads per K-step.
// MODE 0: qkv with scatter epilogue -> Q,K [bh][2048][64], V transposed [bh][64][2048]
// MODE 1: f32 output [M][1024]
template <int MODE>
__global__ __launch_bounds__(256) void gemm_k(
    const u16* __restrict__ A, const u16* __restrict__ Bt,
    const float* __restrict__ bias,
    u16* __restrict__ Qo, u16* __restrict__ Ko, u16* __restrict__ Vt,
    float* __restrict__ Of) {
  __shared__ alignas(16) u16 As[2][128 * 32];
  __shared__ alignas(16) u16 Bs[2][128 * 32];
  const int tid = threadIdx.x;
  const int wid = tid >> 6, lane = tid & 63;
  const int g = lane >> 4, lr = lane & 15;
  const int m0 = blockIdx.y * 128, n0 = blockIdx.x * 128;
  const int wr = (wid >> 1) * 64, wc = (wid & 1) * 64;

  f32x4 acc[4][4];
#pragma unroll
  for (int i = 0; i < 4; ++i)
#pragma unroll
    for (int j = 0; j < 4; ++j) acc[i][j] = (f32x4){0.f, 0.f, 0.f, 0.f};

  const u16* Ab = A + (size_t)m0 * 1024;
  const u16* Bb = Bt + (size_t)n0 * 1024;

  const int srow = tid >> 2, sc = tid & 3;          // staging coords (2 rounds)
  auto stage = [&](int buf, int kt) {
#pragma unroll
    for (int i = 0; i < 2; ++i) {
      int s = tid + i * 256;
      int row = srow + i * 64, c = sc;
      gload16(Ab + (size_t)row * 1024 + kt + c * 8, As[buf] + s * 8);
      gload16(Bb + (size_t)row * 1024 + kt + c * 8, Bs[buf] + s * 8);
    }
  };

  stage(0, 0);
  __syncthreads();  // tile 0 resident
  int cur = 0;
  for (int kt = 0; kt < 1024; kt += 32) {
    if (kt + 32 < 1024) stage(cur ^ 1, kt + 32);  // overlap with compute(t)
    bf16x8 af[4], bfr[4];
#pragma unroll
    for (int i = 0; i < 4; ++i)
      af[i] = *(const bf16x8*)(As[cur] + (wr + i * 16 + lr) * 32 + g * 8);
#pragma unroll
    for (int j = 0; j < 4; ++j)
      bfr[j] = *(const bf16x8*)(Bs[cur] + (wc + j * 16 + lr) * 32 + g * 8);
    __builtin_amdgcn_s_setprio(1);
#pragma unroll
    for (int i = 0; i < 4; ++i)
#pragma unroll
      for (int j = 0; j < 4; ++j)
        acc[i][j] = MFMA16(af[i], bfr[j], acc[i][j]);
    __builtin_amdgcn_s_setprio(0);
    __syncthreads();  // drain stage (vmcnt0) + all waves done reading buf[cur]
    cur ^= 1;
  }

  if constexpr (MODE == 1) {
#pragma unroll
    for (int i = 0; i < 4; ++i) {
      int row = m0 + wr + i * 16 + g * 4;
#pragma unroll
      for (int j = 0; j < 4; ++j) {
        int col = n0 + wc + j * 16 + lr;
        float bv = bias[col];
#pragma unroll
        for (int r = 0; r < 4; ++r)
          Of[(size_t)(row + r) * 1024 + col] = acc[i][j][r] + bv;
      }
    }
  } else {
    const int sel = n0 >> 10;  // 0=Q 1=K 2=V (uniform per block)
#pragma unroll
    for (int i = 0; i < 4; ++i) {
      int row = m0 + wr + i * 16 + g * 4;
      int b = row >> 11, s = row & 2047;
#pragma unroll
      for (int j = 0; j < 4; ++j) {
        int col = n0 + wc + j * 16 + lr;
        float bv = bias[col];
        int nn = col & 1023;
        int h = nn >> 6, hd = nn & 63;
        if (sel == 2) {  // V -> transposed [bh][hd][s], 4 consecutive s per lane
          u16 pk[4];
#pragma unroll
          for (int r = 0; r < 4; ++r) pk[r] = f2bf(acc[i][j][r] + bv);
          uint2 pv;
          pv.x = (u32)pk[0] | ((u32)pk[1] << 16);
          pv.y = (u32)pk[2] | ((u32)pk[3] << 16);
          *(uint2*)(Vt + (size_t)((b * 16 + h) * 64 + hd) * 2048 + s) = pv;
        } else {
          u16* dst = (sel == 0) ? Qo : Ko;
#pragma unroll
          for (int r = 0; r < 4; ++r)
            dst[(size_t)((b * 16 + h) * 2048 + s + r) * 64 + hd] =
                f2bf(acc[i][j][r] + bv);
        }
      }
    }
  }
}

// ---------------- flash attention: 32x32 MFMA, counted-vmcnt 3-buffer pipeline
// grid 512 flat, XCD-chunked: l=(p&7)*64+(p>>3) -> each XCD owns 4 bh
// (K+V = 2MB, L2-resident). Block 256 = 4 waves; wave owns 32 q-rows.
// Per iter: issue stage(t+2) -> s_waitcnt vmcnt(8) (own stage(t) drained;
// stage(t+1)+stage(t+2) stay IN FLIGHT across the barrier) -> raw s_barrier ->
// compute(t) -> raw s_barrier. No vmcnt(0) drain in the loop (T4).
// vmcnt bookkeeping (per-lane VMEM issue order): qf(4) pinned oldest via
// sched_barrier; each stage = 4 loads. iter0 wait vmcnt(8) retires qf+st0;
// steady vmcnt(8) retires st(t); t=30 -> vmcnt(4); t=31 -> vmcnt(0).
// Compute math identical to R6/R9 (verified): swapped QK^T, cancellation-safe
// P-through-LDS PV, defer-max, packed cvt_pk.
__global__ __launch_bounds__(256, 2) void attn_k(const u16* __restrict__ Q,
                                                 const u16* __restrict__ K,
                                                 const u16* __restrict__ Vt,
                                                 u16* __restrict__ O) {
  __shared__ alignas(16) u16 Ks[3][4096];   // 3 bufs [kv][hd], chunk-XOR swizzled
  __shared__ alignas(16) u16 Vs[3][4096];   // 3 bufs [hd][kv], chunk-XOR swizzled
  __shared__ alignas(16) u32 Ps[4 * 1024];  // per-wave [q=32][kv-word=32], swizzled
  const int tid = threadIdx.x;
  const int wid = tid >> 6, lane = tid & 63;
  const int l31 = lane & 31, b5 = lane >> 5;
  const int p = blockIdx.x;
  const int l = (p & 7) * 64 + (p >> 3);  // XCD chunk swizzle (512 % 8 == 0)
  const int qt = l & 15, bh = l >> 4;
  const u16* Qh = Q + (size_t)bh * 2048 * 64;
  const u16* Kh = K + (size_t)bh * 2048 * 64;
  const u16* Vh = Vt + (size_t)bh * 64 * 2048;

  // Q B-frags FIRST (pinned oldest in the per-lane VMEM queue)
  const int qbase = qt * 128 + wid * 32;
  const u16* qp = Qh + (size_t)(qbase + l31) * 64 + b5 * 8;
  bf16x8 qf[4];
#pragma unroll
  for (int c = 0; c < 4; ++c) qf[c] = *(const bf16x8*)(qp + 16 * c);
  __builtin_amdgcn_sched_barrier(0);

  auto stage = [&](int buf, int t) {
#pragma unroll
    for (int i = 0; i < 2; ++i) {
      int s = tid + i * 256;
      int row = s >> 3, c = (s & 7) ^ (row & 7);
      gload16(Kh + (t * 64 + row) * 64 + c * 8, Ks[buf] + s * 8);
      gload16(Vh + row * 2048 + t * 64 + c * 8, Vs[buf] + s * 8);
    }
  };
  stage(0, 0);
  stage(1, 1);

  u32* pw = Ps + wid * 1024 + l31 * 32;
  const int swz = (l31 & 7) << 2;

  f32x16 accO0, accO1;
#pragma unroll
  for (int r = 0; r < 16; ++r) { accO0[r] = 0.f; accO1[r] = 0.f; }
  float mraw = -1e30f;  // running max for q=l31 (raw-score units)
  float mC = 0.f;       // mraw * C2 (exp2 domain)
  float lsum = 0.f;     // per-lane partial denominator

  const float C2 = 0.125f * 1.44269504088896f;  // SCALE * log2(e)

  int cur = 0;
  for (int t = 0; t < 32; ++t) {
    // issue stage(t+2) into buf[(cur+2)%3] (that buffer was last read at t-1,
    // protected by the end-of-iter barrier)
    if (t + 2 < 32) {
      int nxt = cur + 2; if (nxt >= 3) nxt -= 3;
      stage(nxt, t + 2);
    }
    // wait for OWN stage(t) loads only; keep t+1/t+2 in flight across barrier
    if (t < 30)       asm volatile("s_waitcnt vmcnt(8)" ::: "memory");
    else if (t == 30) asm volatile("s_waitcnt vmcnt(4)" ::: "memory");
    else              asm volatile("s_waitcnt vmcnt(0)" ::: "memory");
    __builtin_amdgcn_sched_barrier(0);
    __builtin_amdgcn_s_barrier();   // all waves' stage(t) complete -> buf ready
    __builtin_amdgcn_sched_barrier(0);

    const u16* Kc = Ks[cur];
    const u16* Vc = Vs[cur];

    // QK^T swapped (A=K, B=Q): same claimed layout on both operands.
    f32x16 s0, s1;
#pragma unroll
    for (int r = 0; r < 16; ++r) { s0[r] = 0.f; s1[r] = 0.f; }
    __builtin_amdgcn_s_setprio(1);
#pragma unroll
    for (int c = 0; c < 4; ++c) {
      bf16x8 k0 = ldsfrag(Kc, l31, 2 * c + b5);
      bf16x8 k1 = ldsfrag(Kc, 32 + l31, 2 * c + b5);
      s0 = MFMA32(k0, qf[c], s0);
      s1 = MFMA32(k1, qf[c], s1);
    }
    __builtin_amdgcn_s_setprio(0);

    // lane-local max over this lane's 32 kv values (q = l31)
    float rmax;
    {
      float a0 = fmaxf(fmaxf(s0[0], s0[1]), fmaxf(s0[2], s0[3]));
      float a1 = fmaxf(fmaxf(s0[4], s0[5]), fmaxf(s0[6], s0[7]));
      float a2 = fmaxf(fmaxf(s0[8], s0[9]), fmaxf(s0[10], s0[11]));
      float a3 = fmaxf(fmaxf(s0[12], s0[13]), fmaxf(s0[14], s0[15]));
      float b0 = fmaxf(fmaxf(s1[0], s1[1]), fmaxf(s1[2], s1[3]));
      float b1 = fmaxf(fmaxf(s1[4], s1[5]), fmaxf(s1[6], s1[7]));
      float b2 = fmaxf(fmaxf(s1[8], s1[9]), fmaxf(s1[10], s1[11]));
      float b3 = fmaxf(fmaxf(s1[12], s1[13]), fmaxf(s1[14], s1[15]));
      rmax = fmaxf(fmaxf(fmaxf(a0, a1), fmaxf(a2, a3)),
                   fmaxf(fmaxf(b0, b1), fmaxf(b2, b3)));
    }
    rmax = fmaxf(rmax, __shfl_xor(rmax, 32));  // combine the two kv-subsets

    // defer-max: only rescale when a row grew by > 8 (scaled) = 64 raw
    if (__any(rmax > mraw + 64.f)) {
      float mn = fmaxf(mraw, rmax);
      float al = EXP2((mraw - mn) * C2);
      mraw = mn;
      mC = mn * C2;
      lsum *= al;
#pragma unroll
      for (int r = 0; r < 16; ++r) {
        float ar = __shfl(al, (r & 3) + 8 * (r >> 2) + 4 * b5);
        accO0[r] *= ar;
        accO1[r] *= ar;
      }
    }

    // P = exp2(s*C2 - mC); pack reg-adjacent (=kv-adjacent) pairs; write to
    // per-wave P tile at TRUE kv coords (words (i&1)+4*(i>>1)+2*b5; +16 s1)
    u32 w0[8], w1[8];
#pragma unroll
    for (int i = 0; i < 8; ++i) {
      float p0 = EXP2(__builtin_fmaf(s0[2 * i], C2, -mC));
      float p1 = EXP2(__builtin_fmaf(s0[2 * i + 1], C2, -mC));
      float p2 = EXP2(__builtin_fmaf(s1[2 * i], C2, -mC));
      float p3 = EXP2(__builtin_fmaf(s1[2 * i + 1], C2, -mC));
      lsum += (p0 + p1) + (p2 + p3);
      w0[i] = cvtpk(p0, p1);
      w1[i] = cvtpk(p2, p3);
    }
#pragma unroll
    for (int j = 0; j < 4; ++j) {
      uint2 a; a.x = w0[2 * j]; a.y = w0[2 * j + 1];
      uint2 b; b.x = w1[2 * j]; b.y = w1[2 * j + 1];
      *(uint2*)(pw + ((4 * j + 2 * b5) ^ swz)) = a;        // kv words 4j+2b5,+1
      *(uint2*)(pw + ((16 + 4 * j + 2 * b5) ^ swz)) = b;   // s1 half
    }

    // PV: A-frag (P) and B-frag (V) both read with claimed contiguous-8 ->
    // cancels. Chunk c covers kv 16c..16c+15.
    __builtin_amdgcn_s_setprio(1);
#pragma unroll
    for (int c = 0; c < 4; ++c) {
      bf16x8 pf = *(const bf16x8*)(pw + ((8 * c + 4 * b5) ^ swz));
      bf16x8 v0 = ldsfrag(Vc, l31, 2 * c + b5);
      bf16x8 v1 = ldsfrag(Vc, 32 + l31, 2 * c + b5);
      accO0 = MFMA32(pf, v0, accO0);
      accO1 = MFMA32(pf, v1, accO1);
    }
    __builtin_amdgcn_s_setprio(0);

    __builtin_amdgcn_s_barrier();   // all waves done reading buf[cur]
    __builtin_amdgcn_sched_barrier(0);
    cur += 1; if (cur >= 3) cur -= 3;
  }

  // finish: combine half-lane partial denominators, broadcast 1/l per row
  float ls = lsum + __shfl_xor(lsum, 32);
  float inv = 1.f / ls;
  const int b = bh >> 4, h = bh & 15;
#pragma unroll
  for (int r = 0; r < 16; ++r) {
    float ir = __shfl(inv, (r & 3) + 8 * (r >> 2) + 4 * b5);
    int qr = qbase + (r & 3) + 8 * (r >> 2) + 4 * b5;
    size_t rowoff = (size_t)(b * 2048 + qr) * 1024 + h * 64;
    O[rowoff + l31] = f2bf(accO0[r] * ir);
    O[rowoff + 32 + l31] = f2bf(accO1[r] * ir);
  }
}

extern "C" void kernel_launch(void* const* d_in, const int* in_sizes, int n_in,
                              void* d_out, int out_size, void* d_ws, size_t ws_size,
                              hipStream_t stream) {
  (void)in_sizes; (void)n_in; (void)out_size; (void)ws_size;
  const float* x = (const float*)d_in[0];
  const float* Wqkv = (const float*)d_in[1];
  const float* bqkv = (const float*)d_in[2];
  const float* Wproj = (const float*)d_in[3];
  const float* bproj = (const float*)d_in[4];
  float* out = (float*)d_out;

  char* ws = (char*)d_ws;
  size_t off = 0;
  auto alloc = [&](size_t bytes) {
    void* p = ws + off;
    off += (bytes + 255) & ~(size_t)255;
    return p;
  };
  u16* xb     = (u16*)alloc((size_t)4096 * 1024 * 2);
  u16* Wqkvt  = (u16*)alloc((size_t)3072 * 1024 * 2);
  u16* Wprojt = (u16*)alloc((size_t)1024 * 1024 * 2);
  u16* Qb     = (u16*)alloc((size_t)32 * 2048 * 64 * 2);
  u16* Kb     = (u16*)alloc((size_t)32 * 2048 * 64 * 2);
  u16* Vtb    = (u16*)alloc((size_t)32 * 64 * 2048 * 2);
  u16* AOb    = (u16*)alloc((size_t)4096 * 1024 * 2);

  convert_x<<<2048, 256, 0, stream>>>(x, xb, 4096 * 1024 / 4);
  transpose_w<<<dim3(96, 32), 256, 0, stream>>>(Wqkv, Wqkvt, 1024, 3072);
  transpose_w<<<dim3(32, 32), 256, 0, stream>>>(Wproj, Wprojt, 1024, 1024);
  gemm_k<0><<<dim3(24, 32), 256, 0, stream>>>(xb, Wqkvt, bqkv, Qb, Kb, Vtb, nullptr);
  attn_k<<<512, 256, 0, stream>>>(Qb, Kb, Vtb, AOb);
  gemm_k<1><<<dim3(8, 32), 256, 0, stream>>>(AOb, Wprojt, bproj, nullptr, nullptr, nullptr, out);
}